// Round 6
// baseline (272.566 us; speedup 1.0000x reference)
//
#include <hip/hip_runtime.h>

// DIAGNOSTIC ROUND (R6): three dispatches —
//   1) mct_probe_read : pure-read BW probe (nt loads, 2 passes over x)
//   2) mct_probe_rw   : copy BW probe (nt load x -> nt store ws, 2 passes)
//   3) mct_kernel     : R4 LDS-staged kernel, UNCHANGED control, correct output.
// Context: R1/R3/R4/R5 all floor at ~2.4 TB/s HBM (fill hits 6.6 in same runs).
// TLP, coalescing, and MLP theories all falsified. Probing read vs mixed-RW.

typedef float f4 __attribute__((ext_vector_type(4)));

#define BLOCK 256
#define CHUNK_F4 768       // float4s per block (real kernel)
#define CHUNK_PIX 1024     // pixels per block (real kernel)

// ---------- probe 1: pure read ----------
__global__ __launch_bounds__(BLOCK) void mct_probe_read(
    const float* __restrict__ x, float* __restrict__ ws, long long n4)
{
    const f4* __restrict__ src = reinterpret_cast<const f4*>(x);
    const long long tid    = (long long)blockIdx.x * BLOCK + threadIdx.x;
    const long long stride = (long long)gridDim.x * BLOCK;
    f4 acc = {0.f, 0.f, 0.f, 0.f};
    for (int pass = 0; pass < 2; ++pass) {
        long long i = tid;
        for (; i + 3 * stride < n4; i += 4 * stride) {
            f4 a = __builtin_nontemporal_load(src + i);
            f4 b = __builtin_nontemporal_load(src + i + stride);
            f4 c = __builtin_nontemporal_load(src + i + 2 * stride);
            f4 d = __builtin_nontemporal_load(src + i + 3 * stride);
            acc += a; acc += b; acc += c; acc += d;
        }
        for (; i < n4; i += stride)
            acc += __builtin_nontemporal_load(src + i);
    }
    // keep-live (never true for random normal data sums, compiler can't prove)
    if (acc.x == 1234.5678f && threadIdx.x == 0)
        reinterpret_cast<f4*>(ws)[blockIdx.x] = acc;
}

// ---------- probe 2: copy (read + write) ----------
__global__ __launch_bounds__(BLOCK) void mct_probe_rw(
    const float* __restrict__ x, float* __restrict__ ws,
    long long n4, long long wmask)
{
    const f4* __restrict__ src = reinterpret_cast<const f4*>(x);
    f4* __restrict__ dst = reinterpret_cast<f4*>(ws);
    const long long tid    = (long long)blockIdx.x * BLOCK + threadIdx.x;
    const long long stride = (long long)gridDim.x * BLOCK;
    for (int pass = 0; pass < 2; ++pass) {
        for (long long i = tid; i < n4; i += stride) {
            f4 v = __builtin_nontemporal_load(src + i);
            __builtin_nontemporal_store(v, dst + (i & wmask));
        }
    }
}

// ---------- real kernel: R4 LDS-staged, unchanged ----------
__global__ __launch_bounds__(BLOCK) void mct_kernel(
    const float* __restrict__ x,
    const float* __restrict__ w,
    float* __restrict__ out,
    long long n_full_blocks,
    long long n_pixels)
{
    __shared__ f4 s[CHUNK_F4];
    const int tid = threadIdx.x;
    const long long blk = blockIdx.x;

    const float w00 = w[0], w01 = w[1], w02 = w[2];
    const float w10 = w[3], w11 = w[4], w12 = w[5];
    const float w20 = w[6], w21 = w[7], w22 = w[8];

    if (blk < n_full_blocks) {
        const f4* __restrict__ src = reinterpret_cast<const f4*>(x) + blk * CHUNK_F4;
        s[tid      ] = src[tid      ];
        s[tid + 256] = src[tid + 256];
        s[tid + 512] = src[tid + 512];
        __syncthreads();

        f4 a = s[tid * 3 + 0];
        f4 b = s[tid * 3 + 1];
        f4 c = s[tid * 3 + 2];

        f4 oa, ob, oc;
        oa.x = a.x * w00 + a.y * w10 + a.z * w20;
        oa.y = a.x * w01 + a.y * w11 + a.z * w21;
        oa.z = a.x * w02 + a.y * w12 + a.z * w22;
        oa.w = a.w * w00 + b.x * w10 + b.y * w20;
        ob.x = a.w * w01 + b.x * w11 + b.y * w21;
        ob.y = a.w * w02 + b.x * w12 + b.y * w22;
        ob.z = b.z * w00 + b.w * w10 + c.x * w20;
        ob.w = b.z * w01 + b.w * w11 + c.x * w21;
        oc.x = b.z * w02 + b.w * w12 + c.x * w22;
        oc.y = c.y * w00 + c.z * w10 + c.w * w20;
        oc.z = c.y * w01 + c.z * w11 + c.w * w21;
        oc.w = c.y * w02 + c.z * w12 + c.w * w22;

        s[tid * 3 + 0] = oa;
        s[tid * 3 + 1] = ob;
        s[tid * 3 + 2] = oc;
        __syncthreads();

        f4* dst = reinterpret_cast<f4*>(out) + blk * CHUNK_F4;
        __builtin_nontemporal_store(s[tid      ], dst + tid      );
        __builtin_nontemporal_store(s[tid + 256], dst + tid + 256);
        __builtin_nontemporal_store(s[tid + 512], dst + tid + 512);
    } else {
        long long p = blk * (long long)CHUNK_PIX + tid;
        for (int k = 0; k < 4; ++k, p += 256) {
            if (p < n_pixels) {
                const float x0 = x[p * 3 + 0];
                const float x1 = x[p * 3 + 1];
                const float x2 = x[p * 3 + 2];
                out[p * 3 + 0] = x0 * w00 + x1 * w10 + x2 * w20;
                out[p * 3 + 1] = x0 * w01 + x1 * w11 + x2 * w21;
                out[p * 3 + 2] = x0 * w02 + x1 * w12 + x2 * w22;
            }
        }
    }
}

extern "C" void kernel_launch(void* const* d_in, const int* in_sizes, int n_in,
                              void* d_out, int out_size, void* d_ws, size_t ws_size,
                              hipStream_t stream) {
    const float* x = (const float*)d_in[0];
    const float* w = (const float*)d_in[1];
    float* out = (float*)d_out;
    float* ws  = (float*)d_ws;

    const long long n_total  = (long long)in_sizes[0];   // 32*512*512*3
    const long long n_pixels = n_total / 3;
    const long long n4       = n_total / 4;               // float4 count of x

    // ---- probes ----
    {
        const int pgrid = 2048;
        mct_probe_read<<<pgrid, BLOCK, 0, stream>>>(x, ws, n4);

        // power-of-2 float4 window inside ws
        long long ws4 = (long long)(ws_size / 16);
        if (ws4 > n4) ws4 = n4;
        long long wmask = 1;
        while ((wmask << 1) <= ws4) wmask <<= 1;
        wmask -= 1;                                       // ws4>=1 assumed
        if (ws4 >= 1)
            mct_probe_rw<<<pgrid, BLOCK, 0, stream>>>(x, ws, n4, wmask);
    }

    // ---- real computation (control, unchanged R4 structure) ----
    const long long n_full_blocks = n_pixels / CHUNK_PIX;
    const long long tail_pixels   = n_pixels - n_full_blocks * CHUNK_PIX;
    long long grid = n_full_blocks + (tail_pixels > 0 ? 1 : 0);
    if (grid < 1) grid = 1;

    mct_kernel<<<(int)grid, BLOCK, 0, stream>>>(x, w, out, n_full_blocks, n_pixels);
}

// Round 7
// 179.580 us; speedup vs baseline: 1.5178x; 1.5178x over previous
//
#include <hip/hip_runtime.h>

// out[b,h,w,d] = sum_c x[b,h,w,c] * w[c,d]   with C=D=3, fp32.
//
// R6 probe verdict: copy-structure (grid-stride 2048x256, 1 nt-load ->
// 1 nt-store per iter, lane-stride 16B, no LDS/barriers) sustains
// 36 us/pass (5.5 TB/s app) in-harness — 1.6x faster than every compute
// kernel so far at the SAME HBM traffic profile. So: clone that structure
// exactly and fix the pixel/float4 misalignment with register shuffles.
//
// Lane handles float4 j (stride-1). Pixels straddle float4s; lane needs
// x[4j-2], x[4j-1] (prev lane's .z,.w) and x[4j+4], x[4j+5] (next lane's
// .x,.y) — via __shfl_up/__shfl_down; wave-edge lanes (0,63) patch from
// global (2 scalar loads, L2-hit). Channel phase ph = j%3 selects, per
// output element k (weight column d=(ph+k)%3), the input triple —
// branchless ternaries (v_cndmask), no divergent stores.

typedef float f4 __attribute__((ext_vector_type(4)));

#define BLOCK 256
#define GRID 2048

__global__ __launch_bounds__(BLOCK) void mct_kernel(
    const float* __restrict__ x,
    const float* __restrict__ w,
    float* __restrict__ out,
    long long n4,        // float4 count (n_total/4)
    long long n_total)   // flat float count
{
    const f4* __restrict__ src = reinterpret_cast<const f4*>(x);
    f4* __restrict__ dst = reinterpret_cast<f4*>(out);

    const float w00 = w[0], w01 = w[1], w02 = w[2];
    const float w10 = w[3], w11 = w[4], w12 = w[5];
    const float w20 = w[6], w21 = w[7], w22 = w[8];

    const long long tid    = (long long)blockIdx.x * BLOCK + threadIdx.x;
    const long long stride = (long long)GRID * BLOCK;          // multiple of 64
    const int lane = threadIdx.x & 63;

    // Main loop covers wave-complete float4s only (n4 rounded down to 64).
    const long long n4m = n4 & ~63LL;

    for (long long i = tid; i < n4m; i += stride) {
        f4 v = __builtin_nontemporal_load(src + i);

        // Neighbor-lane boundary elements.
        float pm2 = __shfl_up(v.z, 1);     // x[4j-2]
        float pm1 = __shfl_up(v.w, 1);     // x[4j-1]
        float pp0 = __shfl_down(v.x, 1);   // x[4j+4]
        float pp1 = __shfl_down(v.y, 1);   // x[4j+5]
        if (lane == 0) {
            const long long f = i * 4;
            pm2 = (f >= 2) ? x[f - 2] : 0.f;
            pm1 = (f >= 1) ? x[f - 1] : 0.f;
        }
        if (lane == 63) {
            const long long f = i * 4;
            pp0 = (f + 4 < n_total) ? x[f + 4] : 0.f;
            pp1 = (f + 5 < n_total) ? x[f + 5] : 0.f;
        }

        const int ph = (int)(i % 3);
        const bool p0 = (ph == 0), p1 = (ph == 1);

        f4 o;
        // k=0: ph0: (vx,vy,vz)*col0 | ph1: (pm1,vx,vy)*col1 | ph2: (pm2,pm1,vx)*col2
        {
            float a = p0 ? v.x : (p1 ? pm1 : pm2);
            float b = p0 ? v.y : (p1 ? v.x : pm1);
            float c = p0 ? v.z : (p1 ? v.y : v.x);
            float wa = p0 ? w00 : (p1 ? w01 : w02);
            float wb = p0 ? w10 : (p1 ? w11 : w12);
            float wc = p0 ? w20 : (p1 ? w21 : w22);
            o.x = a * wa + b * wb + c * wc;
        }
        // k=1: ph0: (vx,vy,vz)*col1 | ph1: (pm1,vx,vy)*col2 | ph2: (vy,vz,vw)*col0
        {
            float a = p0 ? v.x : (p1 ? pm1 : v.y);
            float b = p0 ? v.y : (p1 ? v.x : v.z);
            float c = p0 ? v.z : (p1 ? v.y : v.w);
            float wa = p0 ? w01 : (p1 ? w02 : w00);
            float wb = p0 ? w11 : (p1 ? w12 : w10);
            float wc = p0 ? w21 : (p1 ? w22 : w20);
            o.y = a * wa + b * wb + c * wc;
        }
        // k=2: ph0: (vx,vy,vz)*col2 | ph1: (vz,vw,pp0)*col0 | ph2: (vy,vz,vw)*col1
        {
            float a = p0 ? v.x : (p1 ? v.z : v.y);
            float b = p0 ? v.y : (p1 ? v.w : v.z);
            float c = p0 ? v.z : (p1 ? pp0 : v.w);
            float wa = p0 ? w02 : (p1 ? w00 : w01);
            float wb = p0 ? w12 : (p1 ? w10 : w11);
            float wc = p0 ? w22 : (p1 ? w20 : w21);
            o.z = a * wa + b * wb + c * wc;
        }
        // k=3: ph0: (vw,pp0,pp1)*col0 | ph1: (vz,vw,pp0)*col1 | ph2: (vy,vz,vw)*col2
        {
            float a = p0 ? v.w : (p1 ? v.z : v.y);
            float b = p0 ? pp0 : (p1 ? v.w : v.z);
            float c = p0 ? pp1 : (p1 ? pp0 : v.w);
            float wa = p0 ? w00 : (p1 ? w01 : w02);
            float wb = p0 ? w10 : (p1 ? w11 : w12);
            float wc = p0 ? w20 : (p1 ? w21 : w22);
            o.w = a * wa + b * wb + c * wc;
        }

        __builtin_nontemporal_store(o, dst + i);
    }

    // Tail: flats [4*n4m, n_total) — at most 255 elements; block 0 only.
    // (Empty for the bench shape: n4 = 6,291,456 is a multiple of 64.)
    if (blockIdx.x == 0) {
        const long long f = 4 * n4m + threadIdx.x;
        if (f < n_total) {
            const long long p = f / 3;
            const int d = (int)(f - 3 * p);
            const float x0 = x[p * 3 + 0];
            const float x1 = x[p * 3 + 1];
            const float x2 = x[p * 3 + 2];
            out[f] = x0 * w[0 * 3 + d] + x1 * w[1 * 3 + d] + x2 * w[2 * 3 + d];
        }
    }
}

extern "C" void kernel_launch(void* const* d_in, const int* in_sizes, int n_in,
                              void* d_out, int out_size, void* d_ws, size_t ws_size,
                              hipStream_t stream) {
    const float* x = (const float*)d_in[0];
    const float* w = (const float*)d_in[1];
    float* out = (float*)d_out;

    const long long n_total = (long long)in_sizes[0];   // 32*512*512*3
    const long long n4      = n_total / 4;

    mct_kernel<<<GRID, BLOCK, 0, stream>>>(x, w, out, n4, n_total);
}